// Round 2
// baseline (1289.585 us; speedup 1.0000x reference)
//
#include <hip/hip_runtime.h>
#include <hip/hip_bf16.h>

using bf16 = __hip_bfloat16;

// Shapes (fixed): B=32, L=S=96, D=512, H=8, DH=64, d_ff = 9216. M = B*L = 3072.

#define TM 64
#define TN 64
#define TK 32
#define LDA 68   // floats, +4 pad; transposed A tile [TK][LDA]
#define LDB 68   // floats, +4 pad; B tile [TK][LDB]

// load 8 consecutive elements as float
__device__ inline void load8f(const float* p, float v[8]) {
  float4 a = reinterpret_cast<const float4*>(p)[0];
  float4 b = reinterpret_cast<const float4*>(p)[1];
  v[0]=a.x; v[1]=a.y; v[2]=a.z; v[3]=a.w; v[4]=b.x; v[5]=b.y; v[6]=b.z; v[7]=b.w;
}
__device__ inline void load8f(const bf16* p, float v[8]) {
  union { uint4 u; bf16 h[8]; } t;
  t.u = *reinterpret_cast<const uint4*>(p);
  #pragma unroll
  for (int e = 0; e < 8; e++) v[e] = __bfloat162float(t.h[e]);
}

// out(M,N) = X(M,K) @ W(K,N) + bias ; W,bias,out fp32 ; X fp32 or bf16
template <typename InT>
__global__ __launch_bounds__(256) void gemm_bias(
    const InT* __restrict__ X, const float* __restrict__ W,
    const float* __restrict__ bias, float* __restrict__ out,
    int M, int K, int N) {
  __shared__ __align__(16) float As[TK * LDA];
  __shared__ __align__(16) float Bs[TK * LDB];
  const int t  = threadIdx.x;
  const int bm = blockIdx.x * TM;
  const int bn = blockIdx.y * TN;
  const int tr = t >> 4, tc = t & 15;          // 16x16 threads, 4x4 outputs each

  const int arow = t >> 2, acol = (t & 3) * 8; // A: 64 rows x 32 k
  const int brow = t >> 3, bcol = (t & 7) * 8; // B: 32 rows x 64 n

  float acc[4][4] = {};

  for (int k0 = 0; k0 < K; k0 += TK) {
    __syncthreads();
    float av8[8], bv8[8];
    load8f(X + (size_t)(bm + arow) * K + k0 + acol, av8);
    load8f(W + (size_t)(k0 + brow) * N + bn + bcol, bv8);
    #pragma unroll
    for (int e = 0; e < 8; e++) As[(acol + e) * LDA + arow] = av8[e];
    #pragma unroll
    for (int e = 0; e < 8; e++) Bs[brow * LDB + bcol + e] = bv8[e];
    __syncthreads();

    #pragma unroll 8
    for (int kk = 0; kk < TK; kk++) {
      float4 a = *reinterpret_cast<const float4*>(&As[kk * LDA + tr * 4]);
      float4 b = *reinterpret_cast<const float4*>(&Bs[kk * LDB + tc * 4]);
      float av[4] = {a.x, a.y, a.z, a.w};
      float bv[4] = {b.x, b.y, b.z, b.w};
      #pragma unroll
      for (int i = 0; i < 4; i++)
        #pragma unroll
        for (int j = 0; j < 4; j++)
          acc[i][j] += av[i] * bv[j];
    }
  }

  #pragma unroll
  for (int i = 0; i < 4; i++) {
    const int row = bm + tr * 4 + i;
    #pragma unroll
    for (int j = 0; j < 4; j++) {
      const int col = bn + tc * 4 + j;
      out[(size_t)row * N + col] = acc[i][j] + bias[col];
    }
  }
}

// full[b,i,j,k] = (1/8) sum_{n,h} core[n,h]*q[n,b,i,h]*k[n,b,j,h]*v[n,b,k,h]
// raw-reshape indexing: q[n,b,i,h] = QP[n*196608 + b*6144 + i*64 + h]
// One workgroup per (b,i); 256 threads; 6x6 outputs/thread on the 96x96 (j,k) grid.
__global__ __launch_bounds__(256) void stage_b(
    const float* __restrict__ QP, const float* __restrict__ KP,
    const float* __restrict__ VP, const float* __restrict__ core,
    bf16* __restrict__ FULL) {
  const int bi = blockIdx.x;        // 0..3071
  const int b = bi / 96, i = bi % 96;

  __shared__ float aq[512];          // core[n,h]*q[n,b,i,h]/8, n-major
  __shared__ float Ks[96 * 65];      // +1 pad: conflict-free column reads
  __shared__ float Vs[96 * 65];

  const int t = threadIdx.x;
  for (int idx = t; idx < 512; idx += 256) {
    const int n = idx >> 6, h = idx & 63;
    aq[idx] = core[idx] *
              QP[(size_t)n * 196608 + b * 6144 + i * 64 + h] * 0.125f;
  }

  const int tj = (t >> 4) * 6;
  const int tk = (t & 15) * 6;
  float acc[6][6] = {};

  for (int n = 0; n < 8; n++) {
    __syncthreads();                  // protects aq (n=0) and prev-iter Ks/Vs
    const float* Kp = KP + (size_t)n * 196608 + b * 6144;
    const float* Vp = VP + (size_t)n * 196608 + b * 6144;
    for (int idx = t; idx < 6144; idx += 256) {
      const int j = idx >> 6, h = idx & 63;
      Ks[j * 65 + h] = Kp[idx];
      Vs[j * 65 + h] = Vp[idx];
    }
    __syncthreads();

    const float* aqn = aq + n * 64;
    #pragma unroll 2
    for (int h = 0; h < 64; h++) {
      const float av = aqn[h];
      float kj[6], vk[6];
      #pragma unroll
      for (int a = 0; a < 6; a++) kj[a] = av * Ks[(tj + a) * 65 + h];
      #pragma unroll
      for (int c = 0; c < 6; c++) vk[c] = Vs[(tk + c) * 65 + h];
      #pragma unroll
      for (int a = 0; a < 6; a++)
        #pragma unroll
        for (int c = 0; c < 6; c++)
          acc[a][c] += kj[a] * vk[c];
    }
  }

  bf16* outp = FULL + (size_t)bi * 9216;
  #pragma unroll
  for (int a = 0; a < 6; a++)
    #pragma unroll
    for (int c = 0; c < 6; c++)
      outp[(tj + a) * 96 + tk + c] = __float2bfloat16(acc[a][c]);
}

extern "C" void kernel_launch(void* const* d_in, const int* in_sizes, int n_in,
                              void* d_out, int out_size, void* d_ws, size_t ws_size,
                              hipStream_t stream) {
  const float* queries = (const float*)d_in[0];
  const float* keys    = (const float*)d_in[1];
  const float* values  = (const float*)d_in[2];
  // d_in[3] = attn_mask (unused by reference)
  const float* Wq   = (const float*)d_in[4];
  const float* bq   = (const float*)d_in[5];
  const float* Wk   = (const float*)d_in[6];
  const float* bk   = (const float*)d_in[7];
  const float* Wv   = (const float*)d_in[8];
  const float* bv   = (const float*)d_in[9];
  const float* core = (const float*)d_in[10];
  const float* Wo   = (const float*)d_in[11];
  const float* bo   = (const float*)d_in[12];
  float* out = (float*)d_out;

  char* ws = (char*)d_ws;
  float* QP   = (float*)(ws);                 //  6.29 MB (3072*512 f32)
  float* KP   = (float*)(ws + 6291456);       //  6.29 MB
  float* VP   = (float*)(ws + 12582912);      //  6.29 MB
  bf16*  FULL = (bf16*)(ws + 18874368);       // 56.62 MB (3072*9216 bf16)

  const dim3 blk(256);
  const dim3 g1(48, 8);                        // 3072/64 x 512/64

  gemm_bias<float><<<g1, blk, 0, stream>>>(queries, Wq, bq, QP, 3072, 512, 512);
  gemm_bias<float><<<g1, blk, 0, stream>>>(keys,    Wk, bk, KP, 3072, 512, 512);
  gemm_bias<float><<<g1, blk, 0, stream>>>(values,  Wv, bv, VP, 3072, 512, 512);

  stage_b<<<dim3(3072), blk, 0, stream>>>(QP, KP, VP, core, FULL);

  gemm_bias<bf16><<<g1, blk, 0, stream>>>(FULL, Wo, bo, out, 3072, 9216, 512);
}

// Round 3
// 587.788 us; speedup vs baseline: 2.1940x; 2.1940x over previous
//
#include <hip/hip_runtime.h>
#include <hip/hip_bf16.h>

using bf16 = __hip_bfloat16;
typedef float v4f __attribute__((ext_vector_type(4)));
typedef short short8 __attribute__((ext_vector_type(8)));

// Shapes (fixed): B=32, L=S=96, D=512, H=8, DH=64, d_ff=9216. M = B*L = 3072.

// ---------------- projections: fp32 tiled GEMM, OutT = f32 or bf16 ----------
#define TM 64
#define TN 64
#define TK 32
#define PLDA 68
#define PLDB 68

__device__ inline void store_out(float* p, float v) { *p = v; }
__device__ inline void store_out(bf16* p, float v) { *p = __float2bfloat16(v); }

template <typename OutT>
__global__ __launch_bounds__(256) void gemm_bias(
    const float* __restrict__ X, const float* __restrict__ W,
    const float* __restrict__ bias, OutT* __restrict__ out,
    int M, int K, int N) {
  __shared__ __align__(16) float As[TK * PLDA];
  __shared__ __align__(16) float Bs[TK * PLDB];
  const int t  = threadIdx.x;
  const int bm = blockIdx.x * TM;
  const int bn = blockIdx.y * TN;
  const int tr = t >> 4, tc = t & 15;

  const int arow = t >> 2, acol = (t & 3) * 8;
  const int brow = t >> 3, bcol = (t & 7) * 8;

  float acc[4][4] = {};

  for (int k0 = 0; k0 < K; k0 += TK) {
    __syncthreads();
    const float* ap = X + (size_t)(bm + arow) * K + k0 + acol;
    const float* bp = W + (size_t)(k0 + brow) * N + bn + bcol;
    float4 a0 = reinterpret_cast<const float4*>(ap)[0];
    float4 a1 = reinterpret_cast<const float4*>(ap)[1];
    float4 b0 = reinterpret_cast<const float4*>(bp)[0];
    float4 b1 = reinterpret_cast<const float4*>(bp)[1];
    As[(acol + 0) * PLDA + arow] = a0.x; As[(acol + 1) * PLDA + arow] = a0.y;
    As[(acol + 2) * PLDA + arow] = a0.z; As[(acol + 3) * PLDA + arow] = a0.w;
    As[(acol + 4) * PLDA + arow] = a1.x; As[(acol + 5) * PLDA + arow] = a1.y;
    As[(acol + 6) * PLDA + arow] = a1.z; As[(acol + 7) * PLDA + arow] = a1.w;
    *reinterpret_cast<float4*>(&Bs[brow * PLDB + bcol])     = b0;
    *reinterpret_cast<float4*>(&Bs[brow * PLDB + bcol + 4]) = b1;
    __syncthreads();

    #pragma unroll 8
    for (int kk = 0; kk < TK; kk++) {
      float4 a = *reinterpret_cast<const float4*>(&As[kk * PLDA + tr * 4]);
      float4 b = *reinterpret_cast<const float4*>(&Bs[kk * PLDB + tc * 4]);
      float av[4] = {a.x, a.y, a.z, a.w};
      float bv[4] = {b.x, b.y, b.z, b.w};
      #pragma unroll
      for (int i = 0; i < 4; i++)
        #pragma unroll
        for (int j = 0; j < 4; j++)
          acc[i][j] += av[i] * bv[j];
    }
  }

  #pragma unroll
  for (int i = 0; i < 4; i++) {
    const int row = bm + tr * 4 + i;
    #pragma unroll
    for (int j = 0; j < 4; j++) {
      const int col = bn + tc * 4 + j;
      store_out(out + (size_t)row * N + col, acc[i][j] + bias[col]);
    }
  }
}

// ------------- Wo (9216x512 f32) -> WoT (512x9216 bf16), 32x32 LDS tiles ----
__global__ __launch_bounds__(256) void transpose_wo(
    const float* __restrict__ Wo, bf16* __restrict__ WoT) {
  __shared__ bf16 T[32][33];
  const int k0 = blockIdx.x * 32, n0 = blockIdx.y * 32;
  const int t = threadIdx.x;
  const int r = t >> 3, c = (t & 7) * 4;
  float4 v = *reinterpret_cast<const float4*>(Wo + (size_t)(k0 + r) * 512 + n0 + c);
  T[c + 0][r] = __float2bfloat16(v.x);
  T[c + 1][r] = __float2bfloat16(v.y);
  T[c + 2][r] = __float2bfloat16(v.z);
  T[c + 3][r] = __float2bfloat16(v.w);
  __syncthreads();
  union { uint2 u; bf16 h[4]; } o;
  o.h[0] = T[r][c + 0]; o.h[1] = T[r][c + 1];
  o.h[2] = T[r][c + 2]; o.h[3] = T[r][c + 3];
  *reinterpret_cast<uint2*>(WoT + (size_t)(n0 + r) * 9216 + k0 + c) = o.u;
}

// ------------- stage B (MFMA): full[bi] = (aq ⊙ K_b) @ V_b^T ----------------
// raw-reshape indexing: q/k/v[n,b,i,h] = P[n*196608 + b*6144 + i*64 + h]
#define SB_LD 72   // bf16 row stride (96x64 slab, +8 pad)

__global__ __launch_bounds__(256) void stage_b_mfma(
    const float* __restrict__ QP, const bf16* __restrict__ KPb,
    const bf16* __restrict__ VPb, const float* __restrict__ core,
    bf16* __restrict__ FULL) {
  const int bi = blockIdx.x;            // 0..3071
  const int b = bi / 96, i = bi % 96;

  __shared__ float aq[512];
  __shared__ __align__(16) bf16 Ks[96 * SB_LD];
  __shared__ __align__(16) bf16 Vs[96 * SB_LD];

  const int t = threadIdx.x;
  const int w = t >> 6, lane = t & 63;
  const int wr = w >> 1, wc = w & 1;    // 2x2 waves, each 48x48 region
  const int m16 = lane & 15, q = lane >> 4;

  for (int idx = t; idx < 512; idx += 256) {
    const int n = idx >> 6, h = idx & 63;
    aq[idx] = core[idx] * QP[(size_t)n * 196608 + b * 6144 + i * 64 + h] * 0.125f;
  }

  v4f acc[3][3] = {};

  for (int n = 0; n < 8; n++) {
    __syncthreads();                     // aq ready (n=0); prev frag reads done
    const bf16* Kp = KPb + (size_t)n * 196608 + b * 6144;
    const bf16* Vp = VPb + (size_t)n * 196608 + b * 6144;
    const float* aqn = aq + n * 64;
    #pragma unroll
    for (int c = t; c < 768; c += 256) { // 96 rows x 8 chunks of 8 bf16
      const int row = c >> 3, col = (c & 7) * 8;
      union { uint4 u; bf16 h[8]; } kk, ks;
      kk.u = *reinterpret_cast<const uint4*>(Kp + row * 64 + col);
      #pragma unroll
      for (int e = 0; e < 8; e++)
        ks.h[e] = __float2bfloat16(__bfloat162float(kk.h[e]) * aqn[col + e]);
      *reinterpret_cast<uint4*>(&Ks[row * SB_LD + col]) = ks.u;
      *reinterpret_cast<uint4*>(&Vs[row * SB_LD + col]) =
          *reinterpret_cast<const uint4*>(Vp + row * 64 + col);
    }
    __syncthreads();

    #pragma unroll
    for (int s = 0; s < 2; s++) {
      const int koff = s * 32 + q * 8;
      short8 af[3], bf[3];
      #pragma unroll
      for (int a = 0; a < 3; a++)
        af[a] = *reinterpret_cast<const short8*>(
            &Ks[(wr * 48 + a * 16 + m16) * SB_LD + koff]);
      #pragma unroll
      for (int cc = 0; cc < 3; cc++)
        bf[cc] = *reinterpret_cast<const short8*>(
            &Vs[(wc * 48 + cc * 16 + m16) * SB_LD + koff]);
      #pragma unroll
      for (int a = 0; a < 3; a++)
        #pragma unroll
        for (int cc = 0; cc < 3; cc++)
          acc[a][cc] = __builtin_amdgcn_mfma_f32_16x16x32_bf16(
              af[a], bf[cc], acc[a][cc], 0, 0, 0);
    }
  }

  bf16* outp = FULL + (size_t)bi * 9216;
  #pragma unroll
  for (int a = 0; a < 3; a++)
    #pragma unroll
    for (int cc = 0; cc < 3; cc++) {
      const int j0 = wr * 48 + a * 16, k0 = wc * 48 + cc * 16;
      #pragma unroll
      for (int r = 0; r < 4; r++)
        outp[(j0 + q * 4 + r) * 96 + k0 + m16] = __float2bfloat16(acc[a][cc][r]);
    }
}

// ------------- stage C (MFMA): out = FULL @ Wo + bo -------------------------
#define SC_LD 72

__global__ __launch_bounds__(256) void stage_c_mfma(
    const bf16* __restrict__ FULL, const bf16* __restrict__ WoT,
    const float* __restrict__ bo, float* __restrict__ out) {
  const int bm = blockIdx.x * 128, bn = blockIdx.y * 64;
  __shared__ __align__(16) bf16 As[128 * SC_LD];
  __shared__ __align__(16) bf16 Bs[64 * SC_LD];
  const int t = threadIdx.x;
  const int w = t >> 6, lane = t & 63;
  const int m16 = lane & 15, q = lane >> 4;

  v4f acc[2][4] = {};

  for (int k0 = 0; k0 < 9216; k0 += 64) {
    __syncthreads();
    #pragma unroll
    for (int c = t; c < 1024; c += 256) {   // A: 128 rows x 8 chunks
      const int row = c >> 3, col = (c & 7) * 8;
      *reinterpret_cast<uint4*>(&As[row * SC_LD + col]) =
          *reinterpret_cast<const uint4*>(FULL + (size_t)(bm + row) * 9216 + k0 + col);
    }
    #pragma unroll
    for (int c = t; c < 512; c += 256) {    // B: 64 rows x 8 chunks (WoT[n][k])
      const int row = c >> 3, col = (c & 7) * 8;
      *reinterpret_cast<uint4*>(&Bs[row * SC_LD + col]) =
          *reinterpret_cast<const uint4*>(WoT + (size_t)(bn + row) * 9216 + k0 + col);
    }
    __syncthreads();

    #pragma unroll
    for (int s = 0; s < 2; s++) {
      const int koff = s * 32 + q * 8;
      short8 af[2], bfr[4];
      #pragma unroll
      for (int mt = 0; mt < 2; mt++)
        af[mt] = *reinterpret_cast<const short8*>(
            &As[(w * 32 + mt * 16 + m16) * SC_LD + koff]);
      #pragma unroll
      for (int nt = 0; nt < 4; nt++)
        bfr[nt] = *reinterpret_cast<const short8*>(
            &Bs[(nt * 16 + m16) * SC_LD + koff]);
      #pragma unroll
      for (int mt = 0; mt < 2; mt++)
        #pragma unroll
        for (int nt = 0; nt < 4; nt++)
          acc[mt][nt] = __builtin_amdgcn_mfma_f32_16x16x32_bf16(
              af[mt], bfr[nt], acc[mt][nt], 0, 0, 0);
    }
  }

  #pragma unroll
  for (int mt = 0; mt < 2; mt++)
    #pragma unroll
    for (int nt = 0; nt < 4; nt++) {
      #pragma unroll
      for (int r = 0; r < 4; r++) {
        const int row = bm + w * 32 + mt * 16 + q * 4 + r;
        const int col = bn + nt * 16 + m16;
        out[(size_t)row * 512 + col] = acc[mt][nt][r] + bo[col];
      }
    }
}

extern "C" void kernel_launch(void* const* d_in, const int* in_sizes, int n_in,
                              void* d_out, int out_size, void* d_ws, size_t ws_size,
                              hipStream_t stream) {
  const float* queries = (const float*)d_in[0];
  const float* keys    = (const float*)d_in[1];
  const float* values  = (const float*)d_in[2];
  // d_in[3] = attn_mask (unused by reference)
  const float* Wq   = (const float*)d_in[4];
  const float* bq   = (const float*)d_in[5];
  const float* Wk   = (const float*)d_in[6];
  const float* bk   = (const float*)d_in[7];
  const float* Wv   = (const float*)d_in[8];
  const float* bv   = (const float*)d_in[9];
  const float* core = (const float*)d_in[10];
  const float* Wo   = (const float*)d_in[11];
  const float* bo   = (const float*)d_in[12];
  float* out = (float*)d_out;

  char* ws = (char*)d_ws;
  float* QP   = (float*)(ws);                  //  6.29 MB (3072*512 f32)
  bf16*  KPb  = (bf16*)(ws + 6291456);         //  3.15 MB (3072*512 bf16)
  bf16*  VPb  = (bf16*)(ws + 9437184);         //  3.15 MB
  bf16*  WoT  = (bf16*)(ws + 12582912);        //  9.44 MB (512*9216 bf16)
  bf16*  FULL = (bf16*)(ws + 22020096);        // 56.62 MB (3072*9216 bf16)

  const dim3 blk(256);
  const dim3 g1(48, 8);                         // 3072/64 x 512/64

  transpose_wo<<<dim3(288, 16), blk, 0, stream>>>(Wo, WoT);
  gemm_bias<float><<<g1, blk, 0, stream>>>(queries, Wq, bq, QP,  3072, 512, 512);
  gemm_bias<bf16> <<<g1, blk, 0, stream>>>(keys,    Wk, bk, KPb, 3072, 512, 512);
  gemm_bias<bf16> <<<g1, blk, 0, stream>>>(values,  Wv, bv, VPb, 3072, 512, 512);

  stage_b_mfma<<<dim3(3072), blk, 0, stream>>>(QP, KPb, VPb, core, FULL);

  stage_c_mfma<<<dim3(24, 8), blk, 0, stream>>>(FULL, WoT, bo, out);
}

// Round 4
// 282.634 us; speedup vs baseline: 4.5627x; 2.0797x over previous
//
#include <hip/hip_runtime.h>
#include <hip/hip_bf16.h>

using bf16 = __hip_bfloat16;
typedef float v4f __attribute__((ext_vector_type(4)));
typedef short short8 __attribute__((ext_vector_type(8)));

// Shapes (fixed): B=32, L=S=96, D=512, H=8, DH=64, d_ff=9216. M = B*L = 3072.

// ---- transpose + f32->bf16: src (K x N) f32 row-major -> dst (N x K) bf16 --
__global__ __launch_bounds__(256) void transpose_f32_bf16(
    const float* __restrict__ src, bf16* __restrict__ dst, int K, int N) {
  __shared__ bf16 T[32][33];
  const int k0 = blockIdx.x * 32, n0 = blockIdx.y * 32;
  const int t = threadIdx.x;
  const int r = t >> 3, c = (t & 7) * 4;
  float4 v = *reinterpret_cast<const float4*>(src + (size_t)(k0 + r) * N + n0 + c);
  T[c + 0][r] = __float2bfloat16(v.x);
  T[c + 1][r] = __float2bfloat16(v.y);
  T[c + 2][r] = __float2bfloat16(v.z);
  T[c + 3][r] = __float2bfloat16(v.w);
  __syncthreads();
  union { uint2 u; bf16 h[4]; } o;
  o.h[0] = T[r][c + 0]; o.h[1] = T[r][c + 1];
  o.h[2] = T[r][c + 2]; o.h[3] = T[r][c + 3];
  *reinterpret_cast<uint2*>(dst + (size_t)(n0 + r) * K + k0 + c) = o.u;
}

// ---- fused Q/K/V projections (MFMA): O = bf16(X @ W + b), z selects ------
#define PJ_LD 72

__global__ __launch_bounds__(256) void proj_mfma(
    const float* __restrict__ X0, const float* __restrict__ X1,
    const float* __restrict__ X2,
    const bf16* __restrict__ WT0, const bf16* __restrict__ WT1,
    const bf16* __restrict__ WT2,
    const float* __restrict__ b0, const float* __restrict__ b1,
    const float* __restrict__ b2,
    bf16* __restrict__ O0, bf16* __restrict__ O1, bf16* __restrict__ O2) {
  const int z = blockIdx.z;
  const float* X   = z == 0 ? X0  : (z == 1 ? X1  : X2);
  const bf16* WT   = z == 0 ? WT0 : (z == 1 ? WT1 : WT2);
  const float* bia = z == 0 ? b0  : (z == 1 ? b1  : b2);
  bf16* O          = z == 0 ? O0  : (z == 1 ? O1  : O2);

  __shared__ __align__(16) bf16 As[64 * PJ_LD];
  __shared__ __align__(16) bf16 Bs[64 * PJ_LD];
  const int t = threadIdx.x, w = t >> 6, lane = t & 63;
  const int wr = w >> 1, wc = w & 1, m16 = lane & 15, q = lane >> 4;
  const int bm = blockIdx.x * 64, bn = blockIdx.y * 64;

  v4f acc[2][2] = {};

  for (int k0 = 0; k0 < 512; k0 += 64) {
    __syncthreads();
    #pragma unroll
    for (int c = t; c < 1024; c += 256) {     // A: 64x64 f32 -> bf16
      const int row = c >> 4, col = (c & 15) * 4;
      float4 v = *reinterpret_cast<const float4*>(
          X + (size_t)(bm + row) * 512 + k0 + col);
      union { uint2 u; bf16 h[4]; } o;
      o.h[0] = __float2bfloat16(v.x); o.h[1] = __float2bfloat16(v.y);
      o.h[2] = __float2bfloat16(v.z); o.h[3] = __float2bfloat16(v.w);
      *reinterpret_cast<uint2*>(&As[row * PJ_LD + col]) = o.u;
    }
    #pragma unroll
    for (int c = t; c < 512; c += 256) {      // B: WT rows (bf16, contiguous k)
      const int row = c >> 3, col = (c & 7) * 8;
      *reinterpret_cast<uint4*>(&Bs[row * PJ_LD + col]) =
          *reinterpret_cast<const uint4*>(WT + (size_t)(bn + row) * 512 + k0 + col);
    }
    __syncthreads();

    #pragma unroll
    for (int s = 0; s < 2; s++) {
      const int koff = s * 32 + q * 8;
      short8 af[2], bfr[2];
      #pragma unroll
      for (int mt = 0; mt < 2; mt++)
        af[mt] = *reinterpret_cast<const short8*>(
            &As[(wr * 32 + mt * 16 + m16) * PJ_LD + koff]);
      #pragma unroll
      for (int nt = 0; nt < 2; nt++)
        bfr[nt] = *reinterpret_cast<const short8*>(
            &Bs[(wc * 32 + nt * 16 + m16) * PJ_LD + koff]);
      #pragma unroll
      for (int mt = 0; mt < 2; mt++)
        #pragma unroll
        for (int nt = 0; nt < 2; nt++)
          acc[mt][nt] = __builtin_amdgcn_mfma_f32_16x16x32_bf16(
              af[mt], bfr[nt], acc[mt][nt], 0, 0, 0);
    }
  }

  #pragma unroll
  for (int mt = 0; mt < 2; mt++)
    #pragma unroll
    for (int nt = 0; nt < 2; nt++)
      #pragma unroll
      for (int r = 0; r < 4; r++) {
        const int row = bm + wr * 32 + mt * 16 + q * 4 + r;
        const int col = bn + wc * 32 + nt * 16 + m16;
        O[(size_t)row * 512 + col] = __float2bfloat16(acc[mt][nt][r] + bia[col]);
      }
}

// ------------- stage B (MFMA): full[bi] = (aq ⊙ K_b) @ V_b^T ----------------
// raw-reshape indexing: q/k/v[n,b,i,h] = P[n*196608 + b*6144 + i*64 + h]
#define SB_LD 72

__global__ __launch_bounds__(256) void stage_b_mfma(
    const bf16* __restrict__ QPb, const bf16* __restrict__ KPb,
    const bf16* __restrict__ VPb, const float* __restrict__ core,
    bf16* __restrict__ FULL) {
  const int bi = blockIdx.x;            // 0..3071
  const int b = bi / 96, i = bi % 96;

  __shared__ float aq[512];
  __shared__ __align__(16) bf16 Ks[96 * SB_LD];
  __shared__ __align__(16) bf16 Vs[96 * SB_LD];

  const int t = threadIdx.x;
  const int w = t >> 6, lane = t & 63;
  const int wr = w >> 1, wc = w & 1;    // 2x2 waves, each 48x48 region
  const int m16 = lane & 15, q = lane >> 4;

  for (int idx = t; idx < 512; idx += 256) {
    const int n = idx >> 6, h = idx & 63;
    aq[idx] = core[idx] *
              __bfloat162float(QPb[(size_t)n * 196608 + b * 6144 + i * 64 + h]) *
              0.125f;
  }

  v4f acc[3][3] = {};

  for (int n = 0; n < 8; n++) {
    __syncthreads();                     // aq ready (n=0); prev frag reads done
    const bf16* Kp = KPb + (size_t)n * 196608 + b * 6144;
    const bf16* Vp = VPb + (size_t)n * 196608 + b * 6144;
    const float* aqn = aq + n * 64;
    #pragma unroll
    for (int c = t; c < 768; c += 256) { // 96 rows x 8 chunks of 8 bf16
      const int row = c >> 3, col = (c & 7) * 8;
      union { uint4 u; bf16 h[8]; } kk, ks;
      kk.u = *reinterpret_cast<const uint4*>(Kp + row * 64 + col);
      #pragma unroll
      for (int e = 0; e < 8; e++)
        ks.h[e] = __float2bfloat16(__bfloat162float(kk.h[e]) * aqn[col + e]);
      *reinterpret_cast<uint4*>(&Ks[row * SB_LD + col]) = ks.u;
      *reinterpret_cast<uint4*>(&Vs[row * SB_LD + col]) =
          *reinterpret_cast<const uint4*>(Vp + row * 64 + col);
    }
    __syncthreads();

    #pragma unroll
    for (int s = 0; s < 2; s++) {
      const int koff = s * 32 + q * 8;
      short8 af[3], bfr[3];
      #pragma unroll
      for (int a = 0; a < 3; a++)
        af[a] = *reinterpret_cast<const short8*>(
            &Ks[(wr * 48 + a * 16 + m16) * SB_LD + koff]);
      #pragma unroll
      for (int cc = 0; cc < 3; cc++)
        bfr[cc] = *reinterpret_cast<const short8*>(
            &Vs[(wc * 48 + cc * 16 + m16) * SB_LD + koff]);
      #pragma unroll
      for (int a = 0; a < 3; a++)
        #pragma unroll
        for (int cc = 0; cc < 3; cc++)
          acc[a][cc] = __builtin_amdgcn_mfma_f32_16x16x32_bf16(
              af[a], bfr[cc], acc[a][cc], 0, 0, 0);
    }
  }

  bf16* outp = FULL + (size_t)bi * 9216;
  #pragma unroll
  for (int a = 0; a < 3; a++)
    #pragma unroll
    for (int cc = 0; cc < 3; cc++) {
      const int j0 = wr * 48 + a * 16, k0 = wc * 48 + cc * 16;
      #pragma unroll
      for (int r = 0; r < 4; r++)
        outp[(j0 + q * 4 + r) * 96 + k0 + m16] = __float2bfloat16(acc[a][cc][r]);
    }
}

// ---- init out with bias (d_out is poisoned each launch) --------------------
__global__ __launch_bounds__(256) void init_out(
    const float* __restrict__ bo, float* __restrict__ out) {
  const int idx = (blockIdx.x * 256 + threadIdx.x) * 4;   // < 3072*512
  *reinterpret_cast<float4*>(out + idx) =
      *reinterpret_cast<const float4*>(bo + (idx & 511));
}

// ------------- stage C (MFMA, split-K=4): out += FULL @ Wo ------------------
#define SC_LD 72

__global__ __launch_bounds__(256) void stage_c_mfma(
    const bf16* __restrict__ FULL, const bf16* __restrict__ WoT,
    float* __restrict__ out) {
  const int bm = blockIdx.x * 128, bn = blockIdx.y * 64;
  const int kbase = blockIdx.z * 2304;
  __shared__ __align__(16) bf16 As[128 * SC_LD];
  __shared__ __align__(16) bf16 Bs[64 * SC_LD];
  const int t = threadIdx.x;
  const int w = t >> 6, lane = t & 63;
  const int m16 = lane & 15, q = lane >> 4;

  v4f acc[2][4] = {};

  for (int k0 = kbase; k0 < kbase + 2304; k0 += 64) {
    __syncthreads();
    #pragma unroll
    for (int c = t; c < 1024; c += 256) {   // A: 128 rows x 8 chunks
      const int row = c >> 3, col = (c & 7) * 8;
      *reinterpret_cast<uint4*>(&As[row * SC_LD + col]) =
          *reinterpret_cast<const uint4*>(FULL + (size_t)(bm + row) * 9216 + k0 + col);
    }
    #pragma unroll
    for (int c = t; c < 512; c += 256) {    // B: 64 rows x 8 chunks (WoT[n][k])
      const int row = c >> 3, col = (c & 7) * 8;
      *reinterpret_cast<uint4*>(&Bs[row * SC_LD + col]) =
          *reinterpret_cast<const uint4*>(WoT + (size_t)(bn + row) * 9216 + k0 + col);
    }
    __syncthreads();

    #pragma unroll
    for (int s = 0; s < 2; s++) {
      const int koff = s * 32 + q * 8;
      short8 af[2], bfr[4];
      #pragma unroll
      for (int mt = 0; mt < 2; mt++)
        af[mt] = *reinterpret_cast<const short8*>(
            &As[(w * 32 + mt * 16 + m16) * SC_LD + koff]);
      #pragma unroll
      for (int nt = 0; nt < 4; nt++)
        bfr[nt] = *reinterpret_cast<const short8*>(
            &Bs[(nt * 16 + m16) * SC_LD + koff]);
      #pragma unroll
      for (int mt = 0; mt < 2; mt++)
        #pragma unroll
        for (int nt = 0; nt < 4; nt++)
          acc[mt][nt] = __builtin_amdgcn_mfma_f32_16x16x32_bf16(
              af[mt], bfr[nt], acc[mt][nt], 0, 0, 0);
    }
  }

  #pragma unroll
  for (int mt = 0; mt < 2; mt++)
    #pragma unroll
    for (int nt = 0; nt < 4; nt++)
      #pragma unroll
      for (int r = 0; r < 4; r++) {
        const int row = bm + w * 32 + mt * 16 + q * 4 + r;
        const int col = bn + nt * 16 + m16;
        atomicAdd(&out[(size_t)row * 512 + col], acc[mt][nt][r]);
      }
}

extern "C" void kernel_launch(void* const* d_in, const int* in_sizes, int n_in,
                              void* d_out, int out_size, void* d_ws, size_t ws_size,
                              hipStream_t stream) {
  const float* queries = (const float*)d_in[0];
  const float* keys    = (const float*)d_in[1];
  const float* values  = (const float*)d_in[2];
  // d_in[3] = attn_mask (unused by reference)
  const float* Wq   = (const float*)d_in[4];
  const float* bq   = (const float*)d_in[5];
  const float* Wk   = (const float*)d_in[6];
  const float* bk   = (const float*)d_in[7];
  const float* Wv   = (const float*)d_in[8];
  const float* bv   = (const float*)d_in[9];
  const float* core = (const float*)d_in[10];
  const float* Wo   = (const float*)d_in[11];
  const float* bo   = (const float*)d_in[12];
  float* out = (float*)d_out;

  char* ws = (char*)d_ws;
  bf16* QPb = (bf16*)(ws);                   // 3.15 MB (3072*512 bf16)
  bf16* KPb = (bf16*)(ws + 3145728);         // 3.15 MB
  bf16* VPb = (bf16*)(ws + 6291456);         // 3.15 MB
  bf16* WTq = (bf16*)(ws + 9437184);         // 0.52 MB (512*512 bf16)
  bf16* WTk = (bf16*)(ws + 9961472);         // 0.52 MB
  bf16* WTv = (bf16*)(ws + 10485760);        // 0.52 MB
  bf16* WoT = (bf16*)(ws + 11010048);        // 9.44 MB (512*9216 bf16)
  bf16* FULL = (bf16*)(ws + 20447232);       // 56.62 MB (3072*9216 bf16)

  const dim3 blk(256);

  transpose_f32_bf16<<<dim3(16, 16),  blk, 0, stream>>>(Wq, WTq, 512, 512);
  transpose_f32_bf16<<<dim3(16, 16),  blk, 0, stream>>>(Wk, WTk, 512, 512);
  transpose_f32_bf16<<<dim3(16, 16),  blk, 0, stream>>>(Wv, WTv, 512, 512);
  transpose_f32_bf16<<<dim3(288, 16), blk, 0, stream>>>(Wo, WoT, 9216, 512);

  proj_mfma<<<dim3(48, 8, 3), blk, 0, stream>>>(
      queries, keys, values, WTq, WTk, WTv, bq, bk, bv, QPb, KPb, VPb);

  stage_b_mfma<<<dim3(3072), blk, 0, stream>>>(QPb, KPb, VPb, core, FULL);

  init_out<<<dim3(1536), blk, 0, stream>>>(bo, out);
  stage_c_mfma<<<dim3(24, 8, 4), blk, 0, stream>>>(FULL, WoT, out);
}